// Round 7
// baseline (120.544 us; speedup 1.0000x reference)
//
#include <hip/hip_runtime.h>

typedef float f4 __attribute__((ext_vector_type(4)));
typedef short s4 __attribute__((ext_vector_type(4)));
typedef short s8 __attribute__((ext_vector_type(8)));
typedef unsigned int u32;

#define SCALE 0.17677669529663687f
#define XSTRIDE 280  // x^T row stride bytes (128 bf16 + 24 pad); b64-aligned
#define TSTR 144     // Te/Tv row stride bytes (64 bf16 + 16 pad); 16B-aligned

static __device__ __forceinline__ short bf16c(float f) {
  u32 u = __builtin_bit_cast(u32, f);
  u32 r = u + 0x7fffu + ((u >> 16) & 1u);
  return (short)(r >> 16);
}

static __device__ __forceinline__ f4 mfma32(s8 a, s8 b, f4 c) {
  return __builtin_amdgcn_mfma_f32_16x16x32_bf16(a, b, c, 0, 0, 0);
}

// ---------------------------------------------------------------------------
// Kernel A: fused KV 1x1-conv (MFMA) + exp + ctx accumulation.
// Grid (16 chunks, 4 h, 16 b); 256 thr = 4 waves SPLIT BY ROLE:
//   wave 0,1 = K rows [w*16,+16); wave 2,3 = V rows [(w-2)*16,+16).
// Per 64n tile: all waves compute D[64n][16kv] from shared x^T LDS tile
// (wf = 16 regs only); K-waves exp+pack -> Te, V-waves pack -> Tv; then each
// wave does its 16x16 ctx quadrant with true-K=32 MFMA over n.
// Register budget ~95 -> launch_bounds(256,4) => 4 waves/SIMD.
// ---------------------------------------------------------------------------
__global__ __launch_bounds__(256, 4) void ctx_kernel(
    const float* __restrict__ x, const float* __restrict__ wqkv,
    float* __restrict__ cp, float* __restrict__ zp)
{
  const int chunk = blockIdx.x, h = blockIdx.y, b = blockIdx.z;
  const int tid = threadIdx.x, lane = tid & 63, w = tid >> 6;
  __shared__ __align__(16) char xs[64 * XSTRIDE];  // 17920 B
  __shared__ __align__(16) char te[32 * TSTR];     //  4608 B
  __shared__ __align__(16) char tv[32 * TSTR];     //  4608 B

  // B-frags of W^T for this wave's 16 kv rows: lane l -> row grow(l&15),
  // k = kc*32 + (l>>4)*8 + j (contiguous 8 floats -> s8). 16 VGPRs total.
  s8 wf[4];
  {
    const int grow = (w < 2 ? 128 : 256) + h * 32 + (w & 1) * 16 + (lane & 15);
    const int k0 = (lane >> 4) * 8;
#pragma unroll
    for (int kc = 0; kc < 4; ++kc) {
      const float* src = wqkv + grow * 128 + kc * 32 + k0;
      const f4 a = *(const f4*)src;
      const f4 c2 = *(const f4*)(src + 4);
      s8 t = {bf16c(a[0]), bf16c(a[1]), bf16c(a[2]), bf16c(a[3]),
              bf16c(c2[0]), bf16c(c2[1]), bf16c(c2[2]), bf16c(c2[3])};
      wf[kc] = t;
    }
  }

  f4 ctxacc = {0.f, 0.f, 0.f, 0.f};
  float zloc = 0.f;

  const float* xb = x + (size_t)b * 128 * 16384 + chunk * 1024;
  const int nq = tid & 15, ch = tid >> 4;  // staging: n-quad, c-quad
  f4 ld[2][4];                             // prefetch regs (issue-early)

  auto aload = [&](int tl) {
#pragma unroll
    for (int q = 0; q < 2; ++q) {
      const int c0 = ch * 4 + q * 64;
#pragma unroll
      for (int i = 0; i < 4; ++i)
        ld[q][i] = *(const f4*)(xb + (size_t)(c0 + i) * 16384 + tl * 64 + nq * 4);
    }
  };
  auto awrite = [&]() {  // write-late: cvt + transpose into xs
#pragma unroll
    for (int q = 0; q < 2; ++q) {
      const int c0 = ch * 4 + q * 64;
#pragma unroll
      for (int j = 0; j < 4; ++j) {
        s4 t = {bf16c(ld[q][0][j]), bf16c(ld[q][1][j]), bf16c(ld[q][2][j]),
                bf16c(ld[q][3][j])};
        *(s4*)(xs + (nq * 4 + j) * XSTRIDE + c0 * 2) = t;
      }
    }
  };

  const int dh = w >> 1, eh = w & 1;  // ctx quadrant of this wave
  const char* ap = te + (dh * 16 + (lane & 15)) * TSTR + (lane >> 4) * 16;
  const char* bp = tv + (eh * 16 + (lane & 15)) * TSTR + (lane >> 4) * 16;

  aload(0);
  awrite();
  __syncthreads();

  for (int tl = 0; tl < 16; ++tl) {
    if (tl < 15) aload(tl + 1);  // global loads in flight during compute

    // KV GEMM: D[64n][16kv] for this wave's kv rows, nt = 16-row n-subtiles
#pragma unroll
    for (int nt = 0; nt < 4; ++nt) {
      const char* rp = xs + (nt * 16 + (lane & 15)) * XSTRIDE + (lane >> 4) * 16;
      s8 af[4];
#pragma unroll
      for (int kc = 0; kc < 4; ++kc) {
        const s4 lo = *(const s4*)(rp + kc * 64);
        const s4 hi = *(const s4*)(rp + kc * 64 + 8);
        af[kc] = __builtin_shufflevector(lo, hi, 0, 1, 2, 3, 4, 5, 6, 7);
      }
      f4 acc = {0.f, 0.f, 0.f, 0.f};
#pragma unroll
      for (int kc = 0; kc < 4; ++kc) acc = mfma32(af[kc], wf[kc], acc);
      // lane holds kv col (lane&15), n = nt*16 + (lane>>4)*4 + r
      const int wb = (lane & 15) * TSTR + (nt * 16 + (lane >> 4) * 4) * 2;
      if (w < 2) {
        f4 e;
#pragma unroll
        for (int r = 0; r < 4; ++r) e[r] = __expf(acc[r]);
        zloc += e[0] + e[1] + e[2] + e[3];
        s4 t = {bf16c(e[0]), bf16c(e[1]), bf16c(e[2]), bf16c(e[3])};
        *(s4*)(te + w * 16 * TSTR + wb) = t;
      } else {
        s4 t = {bf16c(acc[0]), bf16c(acc[1]), bf16c(acc[2]), bf16c(acc[3])};
        *(s4*)(tv + (w - 2) * 16 * TSTR + wb) = t;
      }
    }
    __syncthreads();  // Te/Tv complete; x-tile reads complete

    // ctx quadrant: contract n (true K=32), 2 chunks of 32
#pragma unroll
    for (int nk = 0; nk < 2; ++nk) {
      const s8 a = *(const s8*)(ap + nk * 64);
      const s8 v = *(const s8*)(bp + nk * 64);
      ctxacc = mfma32(a, v, ctxacc);
    }
    if (tl < 15) awrite();  // overwrite x-tile (reads drained at bar above)
    __syncthreads();        // x-tile ready; Te/Tv reads drained
  }

  // ctx partials: lane -> d = dh*16 + (lane>>4)*4 + r, e = eh*16 + (lane&15)
  {
    const size_t base = (size_t)((b * 4 + h) * 16 + chunk) * 1024;
    const int g4 = (lane >> 4) * 4, cc = lane & 15;
#pragma unroll
    for (int r = 0; r < 4; ++r)
      cp[base + (size_t)(dh * 16 + g4 + r) * 32 + eh * 16 + cc] = ctxacc[r];
  }
  // z partials (K-waves): reduce over the 4 lane-groups sharing d = lane&15
  if (w < 2) {
    float z = zloc;
    z += __shfl_xor(z, 16);
    z += __shfl_xor(z, 32);
    if (lane < 16)
      zp[((b * 4 + h) * 16 + chunk) * 32 + w * 16 + lane] = z;
  }
}

// ---------------------------------------------------------------------------
// Kernel B: reduce chunk partials, normalize, fold
// P_b = SCALE*(W_out·ctx_b)·W_q -> Phi bf16. (round-5 proven version)
// ---------------------------------------------------------------------------
__global__ __launch_bounds__(256, 2) void makeP_full(
    const float* __restrict__ cp, const float* __restrict__ zp,
    const float* __restrict__ wout, const float* __restrict__ wqkv,
    unsigned short* __restrict__ Phi)
{
  const int rg = blockIdx.x, b = blockIdx.y, t = threadIdx.x;
  __shared__ float ctxn[4096];
  __shared__ float zs[128];
  __shared__ float Ms[16][129];

  if (t < 128) {
    float s = 0.f;
#pragma unroll
    for (int ch = 0; ch < 16; ++ch)
      s += zp[((size_t)(b * 4 + (t >> 5)) * 16 + ch) * 32 + (t & 31)];
    zs[t] = s;
  }
  __syncthreads();
  {
    const int i0 = t * 16;
    const int hh = i0 >> 10;
    f4 s0 = {0.f,0.f,0.f,0.f}, s1 = s0, s2 = s0, s3 = s0;
    const float* src = cp + ((size_t)(b * 4 + hh) * 16) * 1024 + (i0 & 1023);
#pragma unroll
    for (int ch = 0; ch < 16; ++ch) {
      const float* p = src + ch * 1024;
      s0 += *(const f4*)(p);
      s1 += *(const f4*)(p + 4);
      s2 += *(const f4*)(p + 8);
      s3 += *(const f4*)(p + 12);
    }
    const float zinv = 1.f / zs[i0 >> 5];
    *(f4*)(ctxn + i0)      = s0 * zinv;
    *(f4*)(ctxn + i0 + 4)  = s1 * zinv;
    *(f4*)(ctxn + i0 + 8)  = s2 * zinv;
    *(f4*)(ctxn + i0 + 12) = s3 * zinv;
  }
  __syncthreads();
  {
    const int o = t >> 4, hd0 = (t & 15) * 8;
    const int hh = hd0 >> 5;
    f4 wseg[8];
    const float* wp = wout + (size_t)(rg * 16 + o) * 128 + hh * 32;
#pragma unroll
    for (int i = 0; i < 8; ++i) wseg[i] = *(const f4*)(wp + i * 4);
#pragma unroll
    for (int j = 0; j < 8; ++j) {
      const float* cn = ctxn + (hd0 + j) * 32;
      f4 acc = {0.f, 0.f, 0.f, 0.f};
#pragma unroll
      for (int i = 0; i < 8; ++i) acc += wseg[i] * *(const f4*)(cn + i * 4);
      Ms[o][hd0 + j] = acc[0] + acc[1] + acc[2] + acc[3];
    }
  }
  __syncthreads();
  {
    const int o = t >> 4, c0 = (t & 15) * 8;
    f4 a0 = {0.f,0.f,0.f,0.f}, a1 = a0;
#pragma unroll 8
    for (int hd = 0; hd < 128; ++hd) {
      const float m = Ms[o][hd];
      const float* wp = wqkv + (size_t)hd * 128 + c0;
      a0 += m * *(const f4*)(wp);
      a1 += m * *(const f4*)(wp + 4);
    }
    a0 *= SCALE;
    a1 *= SCALE;
    s8 out = {bf16c(a0[0]), bf16c(a0[1]), bf16c(a0[2]), bf16c(a0[3]),
              bf16c(a1[0]), bf16c(a1[1]), bf16c(a1[2]), bf16c(a1[3])};
    *(s8*)(Phi + ((size_t)b * 128 + rg * 16 + o) * 128 + c0) = out;
  }
}

// ---------------------------------------------------------------------------
// Kernel C: y[b] = P_b · x[b] + bias as D = x^T · P^T.  (unchanged)
// ---------------------------------------------------------------------------
__global__ __launch_bounds__(256) void out_gemm(
    const float* __restrict__ x, const unsigned short* __restrict__ Phi,
    const float* __restrict__ bias, float* __restrict__ y)
{
  const int nb = blockIdx.x, b = blockIdx.y;
  const int tid = threadIdx.x, lane = tid & 63, w = tid >> 6;
  __shared__ __align__(16) char lds[128 * XSTRIDE];  // 35840 B

  s8 pf[2][4];
#pragma unroll
  for (int ot2 = 0; ot2 < 2; ++ot2) {
    const int orow = (w * 2 + ot2) * 16 + (lane & 15);
#pragma unroll
    for (int kc = 0; kc < 4; ++kc)
      pf[ot2][kc] = *(const s8*)(Phi + ((size_t)b * 128 + orow) * 128 +
                                 kc * 32 + (lane >> 4) * 8);
  }

  const float* xb = x + (size_t)b * 128 * 16384 + (size_t)nb * 128;
  {
    const int nq = tid & 31, ch = tid >> 5;
#pragma unroll
    for (int q = 0; q < 4; ++q) {
      const int c0 = ch * 4 + q * 32;
      f4 v[4];
#pragma unroll
      for (int i = 0; i < 4; ++i)
        v[i] = *(const f4*)(xb + (size_t)(c0 + i) * 16384 + nq * 4);
#pragma unroll
      for (int j = 0; j < 4; ++j) {
        s4 t = {bf16c(v[0][j]), bf16c(v[1][j]), bf16c(v[2][j]), bf16c(v[3][j])};
        *(s4*)(lds + (nq * 4 + j) * XSTRIDE + c0 * 2) = t;
      }
    }
  }
  __syncthreads();

  f4 acc[8][2];
#pragma unroll
  for (int nt = 0; nt < 8; ++nt)
#pragma unroll
    for (int ot2 = 0; ot2 < 2; ++ot2) acc[nt][ot2] = (f4){0.f, 0.f, 0.f, 0.f};

#pragma unroll
  for (int nt = 0; nt < 8; ++nt) {
    const char* rp = lds + (nt * 16 + (lane & 15)) * XSTRIDE + (lane >> 4) * 16;
    s8 af[4];
#pragma unroll
    for (int kc = 0; kc < 4; ++kc) {
      const s4 lo = *(const s4*)(rp + kc * 64);
      const s4 hi = *(const s4*)(rp + kc * 64 + 8);
      af[kc] = __builtin_shufflevector(lo, hi, 0, 1, 2, 3, 4, 5, 6, 7);
    }
#pragma unroll
    for (int kc = 0; kc < 4; ++kc)
#pragma unroll
      for (int ot2 = 0; ot2 < 2; ++ot2)
        acc[nt][ot2] = mfma32(af[kc], pf[ot2][kc], acc[nt][ot2]);
  }

  const int g4 = (lane >> 4) * 4;
#pragma unroll
  for (int ot2 = 0; ot2 < 2; ++ot2) {
    const int o = (w * 2 + ot2) * 16 + (lane & 15);
    const float bv = bias[o];
    float* yo = y + ((size_t)b * 128 + o) * 16384 + (size_t)nb * 128;
#pragma unroll
    for (int nt = 0; nt < 8; ++nt) {
      f4 o4 = acc[nt][ot2];
      o4[0] += bv; o4[1] += bv; o4[2] += bv; o4[3] += bv;
      *(f4*)(yo + nt * 16 + g4) = o4;
    }
  }
}

extern "C" void kernel_launch(void* const* d_in, const int* in_sizes, int n_in,
                              void* d_out, int out_size, void* d_ws, size_t ws_size,
                              hipStream_t stream) {
  const float* x = (const float*)d_in[0];
  const float* wqkv = (const float*)d_in[1];
  const float* wout = (const float*)d_in[2];
  const float* bias = (const float*)d_in[3];
  float* cp = (float*)d_ws;                               // [16][4][16][1024]
  float* zp = cp + 1048576;                               // [16][4][16][32]
  unsigned short* Phi = (unsigned short*)(cp + 1081344);  // [16][128][128] bf16
  float* y = (float*)d_out;

  ctx_kernel<<<dim3(16, 4, 16), 256, 0, stream>>>(x, wqkv, cp, zp);
  makeP_full<<<dim3(8, 16), 256, 0, stream>>>(cp, zp, wout, wqkv, Phi);
  out_gemm<<<dim3(128, 16), 256, 0, stream>>>(x, Phi, bias, y);
}